// Round 22
// baseline (294.747 us; speedup 1.0000x reference)
//
#include <hip/hip_runtime.h>

typedef __attribute__((ext_vector_type(8))) short short8;
typedef __attribute__((ext_vector_type(4))) float f32x4;
typedef __attribute__((ext_vector_type(2))) unsigned u32x2;

#define NN 4096
#define BN_EPS 1e-3f

__device__ inline unsigned short f2bf(float f) {
    unsigned u = __builtin_bit_cast(unsigned, f);
    return (unsigned short)((u + 0x7fffu + ((u >> 16) & 1u)) >> 16);
}
__device__ inline float bf2f(unsigned short h) {
    return __builtin_bit_cast(float, ((unsigned)h) << 16);
}
__device__ inline short8 pk8(f32x4 f0, f32x4 f1) {
    short8 B;
    B[0] = (short)f2bf(f0.x); B[1] = (short)f2bf(f0.y);
    B[2] = (short)f2bf(f0.z); B[3] = (short)f2bf(f0.w);
    B[4] = (short)f2bf(f1.x); B[5] = (short)f2bf(f1.y);
    B[6] = (short)f2bf(f1.z); B[7] = (short)f2bf(f1.w);
    return B;
}

// ---------------------------------------------------------------------------
// MFMA gcn, 2 row-groups/block (A-operand reuse, proven R21: 79 us) + bf16
// adj STORE (layer 1 of big path). Converted bf16 adj written back so layers
// 2/3 read half the bytes from L3-resident cache.
// Block: 256 thr = 4 waves K-split, 32 output rows (2 rgs x 16).
// ---------------------------------------------------------------------------
__global__ __launch_bounds__(256) void n72_gcns(
    const float* __restrict__ adj, const unsigned short* __restrict__ tT,
    unsigned short* __restrict__ adj_bf,
    const float* __restrict__ bias, const float* __restrict__ gamma,
    const float* __restrict__ beta, const float* __restrict__ mean,
    const float* __restrict__ var, unsigned short* __restrict__ xout)
{
    const int tid = threadIdx.x;
    const int s = tid >> 6, lane = tid & 63;
    const int rl = lane & 15, grp = lane >> 4;
    const int bid = blockIdx.x;
    const int b = bid >> 7, rb = bid & 127;
    const int row32 = rb * 32;
    const long aoff = ((long)b * NN + row32 + rl) * (long)NN;

    const float* arow0 = adj + aoff;
    const float* arow1 = arow0 + 16 * (long)NN;
    unsigned short* srow0 = adj_bf + aoff;
    unsigned short* srow1 = srow0 + 16 * (long)NN;
    const unsigned short* t0 = tT + ((long)b * 64 + rl) * (long)NN;
    const unsigned short* t1 = t0 + 16 * (long)NN;
    const unsigned short* t2 = t0 + 32 * (long)NN;
    const unsigned short* t3 = t0 + 48 * (long)NN;
    const int m0 = s * 1024 + grp * 8;

    f32x4 p0 = {}, p1 = {}, p2 = {}, p3 = {};
    f32x4 q0 = {}, q1 = {}, q2 = {}, q3 = {};

    for (int it = 0; it < 32; ++it) {
        const int m = m0 + it * 32;
        short8 A0 = *(const short8*)(t0 + m);
        short8 A1 = *(const short8*)(t1 + m);
        short8 A2 = *(const short8*)(t2 + m);
        short8 A3 = *(const short8*)(t3 + m);
        f32x4 f0 = *(const f32x4*)(arow0 + m);
        f32x4 f1 = *(const f32x4*)(arow0 + m + 4);
        f32x4 g0 = *(const f32x4*)(arow1 + m);
        f32x4 g1 = *(const f32x4*)(arow1 + m + 4);
        short8 B0 = pk8(f0, f1);
        short8 B1 = pk8(g0, g1);
        *(short8*)(srow0 + m) = B0;
        *(short8*)(srow1 + m) = B1;
        p0 = __builtin_amdgcn_mfma_f32_16x16x32_bf16(A0, B0, p0, 0, 0, 0);
        p1 = __builtin_amdgcn_mfma_f32_16x16x32_bf16(A1, B0, p1, 0, 0, 0);
        p2 = __builtin_amdgcn_mfma_f32_16x16x32_bf16(A2, B0, p2, 0, 0, 0);
        p3 = __builtin_amdgcn_mfma_f32_16x16x32_bf16(A3, B0, p3, 0, 0, 0);
        q0 = __builtin_amdgcn_mfma_f32_16x16x32_bf16(A0, B1, q0, 0, 0, 0);
        q1 = __builtin_amdgcn_mfma_f32_16x16x32_bf16(A1, B1, q1, 0, 0, 0);
        q2 = __builtin_amdgcn_mfma_f32_16x16x32_bf16(A2, B1, q2, 0, 0, 0);
        q3 = __builtin_amdgcn_mfma_f32_16x16x32_bf16(A3, B1, q3, 0, 0, 0);
    }

    __shared__ float red[4][2][16][68];
    *(f32x4*)&red[s][0][rl][ 0 + grp * 4] = p0;
    *(f32x4*)&red[s][0][rl][16 + grp * 4] = p1;
    *(f32x4*)&red[s][0][rl][32 + grp * 4] = p2;
    *(f32x4*)&red[s][0][rl][48 + grp * 4] = p3;
    *(f32x4*)&red[s][1][rl][ 0 + grp * 4] = q0;
    *(f32x4*)&red[s][1][rl][16 + grp * 4] = q1;
    *(f32x4*)&red[s][1][rl][32 + grp * 4] = q2;
    *(f32x4*)&red[s][1][rl][48 + grp * 4] = q3;
    __syncthreads();

    const int r2 = tid >> 4, cq = (tid & 15) * 4;
    f32x4 bi = *(const f32x4*)(bias + cq);
    f32x4 mn = *(const f32x4*)(mean + cq);
    f32x4 vr = *(const f32x4*)(var + cq);
    f32x4 gm = *(const f32x4*)(gamma + cq);
    f32x4 bt = *(const f32x4*)(beta + cq);
    f32x4 sc;
    for (int q = 0; q < 4; ++q) sc[q] = gm[q] / sqrtf(vr[q] + BN_EPS);

    for (int rg = 0; rg < 2; ++rg) {
        f32x4 v = *(const f32x4*)&red[0][rg][r2][cq];
        v += *(const f32x4*)&red[1][rg][r2][cq];
        v += *(const f32x4*)&red[2][rg][r2][cq];
        v += *(const f32x4*)&red[3][rg][r2][cq];
        float o[4];
        for (int q = 0; q < 4; ++q) {
            float h = v[q] + bi[q];
            h = h > 0.f ? h : 0.f;
            o[q] = (h - mn[q]) * sc[q] + bt[q];
        }
        u32x2 o2;
        o2.x = (unsigned)f2bf(o[0]) | ((unsigned)f2bf(o[1]) << 16);
        o2.y = (unsigned)f2bf(o[2]) | ((unsigned)f2bf(o[3]) << 16);
        *(u32x2*)(xout + ((long)b * NN + row32 + rg * 16 + r2) * 64 + cq) = o2;
    }
}

// ---------------------------------------------------------------------------
// MFMA gcn, 2 rgs/block, bf16 adj (layers 2-3): 4 A + 2 B requests/window,
// half the B bytes, L3-resident.
// ---------------------------------------------------------------------------
__global__ __launch_bounds__(256) void n72_gcnb(
    const unsigned short* __restrict__ adj, const unsigned short* __restrict__ tT,
    const float* __restrict__ bias, const float* __restrict__ gamma,
    const float* __restrict__ beta, const float* __restrict__ mean,
    const float* __restrict__ var, unsigned short* __restrict__ xout)
{
    const int tid = threadIdx.x;
    const int s = tid >> 6, lane = tid & 63;
    const int rl = lane & 15, grp = lane >> 4;
    const int bid = blockIdx.x;
    const int b = bid >> 7, rb = bid & 127;
    const int row32 = rb * 32;

    const unsigned short* arow0 = adj + ((long)b * NN + row32 + rl) * (long)NN;
    const unsigned short* arow1 = arow0 + 16 * (long)NN;
    const unsigned short* t0 = tT + ((long)b * 64 + rl) * (long)NN;
    const unsigned short* t1 = t0 + 16 * (long)NN;
    const unsigned short* t2 = t0 + 32 * (long)NN;
    const unsigned short* t3 = t0 + 48 * (long)NN;
    const int m0 = s * 1024 + grp * 8;

    f32x4 p0 = {}, p1 = {}, p2 = {}, p3 = {};
    f32x4 q0 = {}, q1 = {}, q2 = {}, q3 = {};

    for (int it = 0; it < 32; ++it) {
        const int m = m0 + it * 32;
        short8 A0 = *(const short8*)(t0 + m);
        short8 A1 = *(const short8*)(t1 + m);
        short8 A2 = *(const short8*)(t2 + m);
        short8 A3 = *(const short8*)(t3 + m);
        short8 B0 = *(const short8*)(arow0 + m);
        short8 B1 = *(const short8*)(arow1 + m);
        p0 = __builtin_amdgcn_mfma_f32_16x16x32_bf16(A0, B0, p0, 0, 0, 0);
        p1 = __builtin_amdgcn_mfma_f32_16x16x32_bf16(A1, B0, p1, 0, 0, 0);
        p2 = __builtin_amdgcn_mfma_f32_16x16x32_bf16(A2, B0, p2, 0, 0, 0);
        p3 = __builtin_amdgcn_mfma_f32_16x16x32_bf16(A3, B0, p3, 0, 0, 0);
        q0 = __builtin_amdgcn_mfma_f32_16x16x32_bf16(A0, B1, q0, 0, 0, 0);
        q1 = __builtin_amdgcn_mfma_f32_16x16x32_bf16(A1, B1, q1, 0, 0, 0);
        q2 = __builtin_amdgcn_mfma_f32_16x16x32_bf16(A2, B1, q2, 0, 0, 0);
        q3 = __builtin_amdgcn_mfma_f32_16x16x32_bf16(A3, B1, q3, 0, 0, 0);
    }

    __shared__ float red[4][2][16][68];
    *(f32x4*)&red[s][0][rl][ 0 + grp * 4] = p0;
    *(f32x4*)&red[s][0][rl][16 + grp * 4] = p1;
    *(f32x4*)&red[s][0][rl][32 + grp * 4] = p2;
    *(f32x4*)&red[s][0][rl][48 + grp * 4] = p3;
    *(f32x4*)&red[s][1][rl][ 0 + grp * 4] = q0;
    *(f32x4*)&red[s][1][rl][16 + grp * 4] = q1;
    *(f32x4*)&red[s][1][rl][32 + grp * 4] = q2;
    *(f32x4*)&red[s][1][rl][48 + grp * 4] = q3;
    __syncthreads();

    const int r2 = tid >> 4, cq = (tid & 15) * 4;
    f32x4 bi = *(const f32x4*)(bias + cq);
    f32x4 mn = *(const f32x4*)(mean + cq);
    f32x4 vr = *(const f32x4*)(var + cq);
    f32x4 gm = *(const f32x4*)(gamma + cq);
    f32x4 bt = *(const f32x4*)(beta + cq);
    f32x4 sc;
    for (int q = 0; q < 4; ++q) sc[q] = gm[q] / sqrtf(vr[q] + BN_EPS);

    for (int rg = 0; rg < 2; ++rg) {
        f32x4 v = *(const f32x4*)&red[0][rg][r2][cq];
        v += *(const f32x4*)&red[1][rg][r2][cq];
        v += *(const f32x4*)&red[2][rg][r2][cq];
        v += *(const f32x4*)&red[3][rg][r2][cq];
        float o[4];
        for (int q = 0; q < 4; ++q) {
            float h = v[q] + bi[q];
            h = h > 0.f ? h : 0.f;
            o[q] = (h - mn[q]) * sc[q] + bt[q];
        }
        u32x2 o2;
        o2.x = (unsigned)f2bf(o[0]) | ((unsigned)f2bf(o[1]) << 16);
        o2.y = (unsigned)f2bf(o[2]) | ((unsigned)f2bf(o[3]) << 16);
        *(u32x2*)(xout + ((long)b * NN + row32 + rg * 16 + r2) * 64 + cq) = o2;
    }
}

// ---------------------------------------------------------------------------
// Fallback: proven R21 kernel (fp32 adj, no store).
// ---------------------------------------------------------------------------
__global__ __launch_bounds__(256) void n72_gcn(
    const float* __restrict__ adj, const unsigned short* __restrict__ tT,
    const float* __restrict__ bias, const float* __restrict__ gamma,
    const float* __restrict__ beta, const float* __restrict__ mean,
    const float* __restrict__ var, unsigned short* __restrict__ xout)
{
    const int tid = threadIdx.x;
    const int s = tid >> 6, lane = tid & 63;
    const int rl = lane & 15, grp = lane >> 4;
    const int bid = blockIdx.x;
    const int b = bid >> 7, rb = bid & 127;
    const int row32 = rb * 32;

    const float* arow0 = adj + ((long)b * NN + row32 + rl) * (long)NN;
    const float* arow1 = arow0 + 16 * (long)NN;
    const unsigned short* t0 = tT + ((long)b * 64 + rl) * (long)NN;
    const unsigned short* t1 = t0 + 16 * (long)NN;
    const unsigned short* t2 = t0 + 32 * (long)NN;
    const unsigned short* t3 = t0 + 48 * (long)NN;
    const int m0 = s * 1024 + grp * 8;

    f32x4 p0 = {}, p1 = {}, p2 = {}, p3 = {};
    f32x4 q0 = {}, q1 = {}, q2 = {}, q3 = {};

    for (int it = 0; it < 32; ++it) {
        const int m = m0 + it * 32;
        short8 A0 = *(const short8*)(t0 + m);
        short8 A1 = *(const short8*)(t1 + m);
        short8 A2 = *(const short8*)(t2 + m);
        short8 A3 = *(const short8*)(t3 + m);
        f32x4 f0 = *(const f32x4*)(arow0 + m);
        f32x4 f1 = *(const f32x4*)(arow0 + m + 4);
        f32x4 g0 = *(const f32x4*)(arow1 + m);
        f32x4 g1 = *(const f32x4*)(arow1 + m + 4);
        short8 B0 = pk8(f0, f1);
        short8 B1 = pk8(g0, g1);
        p0 = __builtin_amdgcn_mfma_f32_16x16x32_bf16(A0, B0, p0, 0, 0, 0);
        p1 = __builtin_amdgcn_mfma_f32_16x16x32_bf16(A1, B0, p1, 0, 0, 0);
        p2 = __builtin_amdgcn_mfma_f32_16x16x32_bf16(A2, B0, p2, 0, 0, 0);
        p3 = __builtin_amdgcn_mfma_f32_16x16x32_bf16(A3, B0, p3, 0, 0, 0);
        q0 = __builtin_amdgcn_mfma_f32_16x16x32_bf16(A0, B1, q0, 0, 0, 0);
        q1 = __builtin_amdgcn_mfma_f32_16x16x32_bf16(A1, B1, q1, 0, 0, 0);
        q2 = __builtin_amdgcn_mfma_f32_16x16x32_bf16(A2, B1, q2, 0, 0, 0);
        q3 = __builtin_amdgcn_mfma_f32_16x16x32_bf16(A3, B1, q3, 0, 0, 0);
    }

    __shared__ float red[4][2][16][68];
    *(f32x4*)&red[s][0][rl][ 0 + grp * 4] = p0;
    *(f32x4*)&red[s][0][rl][16 + grp * 4] = p1;
    *(f32x4*)&red[s][0][rl][32 + grp * 4] = p2;
    *(f32x4*)&red[s][0][rl][48 + grp * 4] = p3;
    *(f32x4*)&red[s][1][rl][ 0 + grp * 4] = q0;
    *(f32x4*)&red[s][1][rl][16 + grp * 4] = q1;
    *(f32x4*)&red[s][1][rl][32 + grp * 4] = q2;
    *(f32x4*)&red[s][1][rl][48 + grp * 4] = q3;
    __syncthreads();

    const int r2 = tid >> 4, cq = (tid & 15) * 4;
    f32x4 bi = *(const f32x4*)(bias + cq);
    f32x4 mn = *(const f32x4*)(mean + cq);
    f32x4 vr = *(const f32x4*)(var + cq);
    f32x4 gm = *(const f32x4*)(gamma + cq);
    f32x4 bt = *(const f32x4*)(beta + cq);
    f32x4 sc;
    for (int q = 0; q < 4; ++q) sc[q] = gm[q] / sqrtf(vr[q] + BN_EPS);

    for (int rg = 0; rg < 2; ++rg) {
        f32x4 v = *(const f32x4*)&red[0][rg][r2][cq];
        v += *(const f32x4*)&red[1][rg][r2][cq];
        v += *(const f32x4*)&red[2][rg][r2][cq];
        v += *(const f32x4*)&red[3][rg][r2][cq];
        float o[4];
        for (int q = 0; q < 4; ++q) {
            float h = v[q] + bi[q];
            h = h > 0.f ? h : 0.f;
            o[q] = (h - mn[q]) * sc[q] + bt[q];
        }
        u32x2 o2;
        o2.x = (unsigned)f2bf(o[0]) | ((unsigned)f2bf(o[1]) << 16);
        o2.y = (unsigned)f2bf(o[2]) | ((unsigned)f2bf(o[3]) << 16);
        *(u32x2*)(xout + ((long)b * NN + row32 + rg * 16 + r2) * 64 + cq) = o2;
    }
}

// ---------------------------------------------------------------------------
// Feature transform: tT[b][c][n] = sum_k xin[b][n][k] * W[k][c]  (bf16 out)
// ---------------------------------------------------------------------------
__global__ __launch_bounds__(256) void h72_feat32(
    const float* __restrict__ xin, const float* __restrict__ W,
    unsigned short* __restrict__ tT)
{
    __shared__ float xs[64][68];
    __shared__ float Ws[64][68];
    const int tid = threadIdx.x;
    const int bid = blockIdx.x;
    const int b = bid >> 6, nb = bid & 63;
    {
        const int rr = tid >> 2, kq = (tid & 3) * 16;
        const float* xp = xin + ((long)b * NN + nb * 64 + rr) * 64 + kq;
        const float* wp = W + rr * 64 + kq;
        for (int j = 0; j < 4; ++j) {
            *(f32x4*)&xs[rr][kq + j * 4] = *(const f32x4*)(xp + j * 4);
            *(f32x4*)&Ws[rr][kq + j * 4] = *(const f32x4*)(wp + j * 4);
        }
    }
    __syncthreads();
    const int c = tid >> 2, n0 = (tid & 3) * 16;
    float outv[16];
    for (int j = 0; j < 16; ++j) outv[j] = 0.f;
    for (int kt = 0; kt < 4; ++kt) {
        float wc[16];
#pragma unroll
        for (int kk = 0; kk < 16; ++kk) wc[kk] = Ws[kt * 16 + kk][c];
#pragma unroll
        for (int j = 0; j < 16; ++j)
#pragma unroll
            for (int kk = 0; kk < 16; ++kk)
                outv[j] += xs[n0 + j][kt * 16 + kk] * wc[kk];
    }
    unsigned short* tp = tT + ((long)b * 64 + c) * (long)NN + nb * 64 + n0;
#pragma unroll
    for (int j = 0; j < 16; j += 2)
        *(unsigned*)(tp + j) =
            (unsigned)f2bf(outv[j]) | ((unsigned)f2bf(outv[j + 1]) << 16);
}

__global__ __launch_bounds__(256) void h72_featbf(
    const unsigned short* __restrict__ xin, const float* __restrict__ W,
    unsigned short* __restrict__ tT)
{
    __shared__ float xs[64][68];
    __shared__ float Ws[64][68];
    const int tid = threadIdx.x;
    const int bid = blockIdx.x;
    const int b = bid >> 6, nb = bid & 63;
    {
        const int rr = tid >> 2, kq = (tid & 3) * 16;
        const unsigned short* xp = xin + ((long)b * NN + nb * 64 + rr) * 64 + kq;
        const float* wp = W + rr * 64 + kq;
        short8 v0 = *(const short8*)(xp);
        short8 v1 = *(const short8*)(xp + 8);
        for (int j = 0; j < 8; ++j) {
            xs[rr][kq + j]     = bf2f((unsigned short)v0[j]);
            xs[rr][kq + 8 + j] = bf2f((unsigned short)v1[j]);
        }
        for (int j = 0; j < 4; ++j)
            *(f32x4*)&Ws[rr][kq + j * 4] = *(const f32x4*)(wp + j * 4);
    }
    __syncthreads();
    const int c = tid >> 2, n0 = (tid & 3) * 16;
    float outv[16];
    for (int j = 0; j < 16; ++j) outv[j] = 0.f;
    for (int kt = 0; kt < 4; ++kt) {
        float wc[16];
#pragma unroll
        for (int kk = 0; kk < 16; ++kk) wc[kk] = Ws[kt * 16 + kk][c];
#pragma unroll
        for (int j = 0; j < 16; ++j)
#pragma unroll
            for (int kk = 0; kk < 16; ++kk)
                outv[j] += xs[n0 + j][kt * 16 + kk] * wc[kk];
    }
    unsigned short* tp = tT + ((long)b * 64 + c) * (long)NN + nb * 64 + n0;
#pragma unroll
    for (int j = 0; j < 16; j += 2)
        *(unsigned*)(tp + j) =
            (unsigned)f2bf(outv[j]) | ((unsigned)f2bf(outv[j + 1]) << 16);
}

// ---------------------------------------------------------------------------
// Final MLP: out = relu(concat(x1,x2,x3) @ Wl + bl) -> FLOAT32 output
// ---------------------------------------------------------------------------
__global__ __launch_bounds__(256) void h72_mlp(
    const unsigned short* __restrict__ x1, const unsigned short* __restrict__ x2,
    const unsigned short* __restrict__ x3, const float* __restrict__ Wl,
    const float* __restrict__ bl, float* __restrict__ out)
{
    __shared__ float hs[64][196];
    const int tid = threadIdx.x;
    const int bid = blockIdx.x;
    const int b = bid >> 6, nb = bid & 63;
    {
        const int rr = tid >> 2, kq = (tid & 3) * 16;
        const long base = ((long)b * NN + nb * 64 + rr) * 64 + kq;
        short8 u0 = *(const short8*)(x1 + base);
        short8 u1 = *(const short8*)(x1 + base + 8);
        short8 v0 = *(const short8*)(x2 + base);
        short8 v1 = *(const short8*)(x2 + base + 8);
        short8 w0 = *(const short8*)(x3 + base);
        short8 w1 = *(const short8*)(x3 + base + 8);
        for (int j = 0; j < 8; ++j) {
            hs[rr][  0 + kq + j]     = bf2f((unsigned short)u0[j]);
            hs[rr][  0 + kq + 8 + j] = bf2f((unsigned short)u1[j]);
            hs[rr][ 64 + kq + j]     = bf2f((unsigned short)v0[j]);
            hs[rr][ 64 + kq + 8 + j] = bf2f((unsigned short)v1[j]);
            hs[rr][128 + kq + j]     = bf2f((unsigned short)w0[j]);
            hs[rr][128 + kq + 8 + j] = bf2f((unsigned short)w1[j]);
        }
    }
    __syncthreads();
    const int c = tid >> 2, n0 = (tid & 3) * 16;
    float acc[16];
    const float blc = bl[c];
    for (int j = 0; j < 16; ++j) acc[j] = blc;
    for (int kt = 0; kt < 12; ++kt) {
        float wc[16];
#pragma unroll
        for (int kk = 0; kk < 16; ++kk) wc[kk] = Wl[(kt * 16 + kk) * 64 + c];
#pragma unroll
        for (int j = 0; j < 16; ++j)
#pragma unroll
            for (int kk = 0; kk < 16; ++kk)
                acc[j] += hs[n0 + j][kt * 16 + kk] * wc[kk];
    }
    float* op = out + ((long)b * NN + nb * 64 + n0) * 64 + c;
#pragma unroll
    for (int j = 0; j < 16; ++j) {
        float v2 = acc[j] > 0.f ? acc[j] : 0.f;
        op[j * 64] = v2;
    }
}

// ---------------------------------------------------------------------------
extern "C" void kernel_launch(void* const* d_in, const int* in_sizes, int n_in,
                              void* d_out, int out_size, void* d_ws, size_t ws_size,
                              hipStream_t stream)
{
    (void)in_sizes; (void)n_in; (void)out_size;
    const float* x   = (const float*)d_in[0];
    const float* adj = (const float*)d_in[1];
    const float* W1  = (const float*)d_in[2];
    const float* b1  = (const float*)d_in[3];
    const float* g1  = (const float*)d_in[4];
    const float* be1 = (const float*)d_in[5];
    const float* m1  = (const float*)d_in[6];
    const float* v1  = (const float*)d_in[7];
    const float* W2  = (const float*)d_in[8];
    const float* b2  = (const float*)d_in[9];
    const float* g2  = (const float*)d_in[10];
    const float* be2 = (const float*)d_in[11];
    const float* m2  = (const float*)d_in[12];
    const float* v2  = (const float*)d_in[13];
    const float* W3  = (const float*)d_in[14];
    const float* b3  = (const float*)d_in[15];
    const float* g3  = (const float*)d_in[16];
    const float* be3 = (const float*)d_in[17];
    const float* m3  = (const float*)d_in[18];
    const float* v3  = (const float*)d_in[19];
    const float* Wl  = (const float*)d_in[20];
    const float* bl  = (const float*)d_in[21];

    // OUTPUT IS FLOAT32: 1048576 floats = 4 MB. tT (bf16, 2 MB) lives in
    // d_out's second half; h72_mlp overwrites all of d_out last.
    float* out = (float*)d_out;
    unsigned short* tT = (unsigned short*)(out + 524288);

    char* ws = (char*)d_ws;
    unsigned short* x1 = (unsigned short*)(ws);
    unsigned short* x2 = (unsigned short*)(ws + 2097152);
    unsigned short* x3 = (unsigned short*)(ws + 4194304);
    unsigned short* adjbf = (unsigned short*)(ws + 6291456);
    const size_t NEED_BIG = 6291456 + (size_t)4 * NN * NN * 2;   // ~140 MB

    if (ws_size >= NEED_BIG) {
        h72_feat32<<<256, 256, 0, stream>>>(x, W1, tT);
        n72_gcns<<<512, 256, 0, stream>>>(adj, tT, adjbf, b1, g1, be1, m1, v1, x1);

        h72_featbf<<<256, 256, 0, stream>>>(x1, W2, tT);
        n72_gcnb<<<512, 256, 0, stream>>>(adjbf, tT, b2, g2, be2, m2, v2, x2);

        h72_featbf<<<256, 256, 0, stream>>>(x2, W3, tT);
        n72_gcnb<<<512, 256, 0, stream>>>(adjbf, tT, b3, g3, be3, m3, v3, x3);

        h72_mlp<<<256, 256, 0, stream>>>(x1, x2, x3, Wl, bl, out);
    } else {
        h72_feat32<<<256, 256, 0, stream>>>(x, W1, tT);
        n72_gcn<<<512, 256, 0, stream>>>(adj, tT, b1, g1, be1, m1, v1, x1);

        h72_featbf<<<256, 256, 0, stream>>>(x1, W2, tT);
        n72_gcn<<<512, 256, 0, stream>>>(adj, tT, b2, g2, be2, m2, v2, x2);

        h72_featbf<<<256, 256, 0, stream>>>(x2, W3, tT);
        n72_gcn<<<512, 256, 0, stream>>>(adj, tT, b3, g3, be3, m3, v3, x3);

        h72_mlp<<<256, 256, 0, stream>>>(x1, x2, x3, Wl, bl, out);
    }
}

// Round 23
// 225.142 us; speedup vs baseline: 1.3092x; 1.3092x over previous
//
#include <hip/hip_runtime.h>

typedef __attribute__((ext_vector_type(8))) short short8;
typedef __attribute__((ext_vector_type(4))) float f32x4;
typedef __attribute__((ext_vector_type(2))) unsigned u32x2;

#define NN 4096
#define BN_EPS 1e-3f

__device__ inline unsigned short f2bf(float f) {
    unsigned u = __builtin_bit_cast(unsigned, f);
    return (unsigned short)((u + 0x7fffu + ((u >> 16) & 1u)) >> 16);
}
__device__ inline float bf2f(unsigned short h) {
    return __builtin_bit_cast(float, ((unsigned)h) << 16);
}
__device__ inline short8 pk8(f32x4 f0, f32x4 f1) {
    short8 B;
    B[0] = (short)f2bf(f0.x); B[1] = (short)f2bf(f0.y);
    B[2] = (short)f2bf(f0.z); B[3] = (short)f2bf(f0.w);
    B[4] = (short)f2bf(f1.x); B[5] = (short)f2bf(f1.y);
    B[6] = (short)f2bf(f1.z); B[7] = (short)f2bf(f1.w);
    return B;
}

// ---------------------------------------------------------------------------
// MFMA gcn, 4 row-groups per block (max A-operand reuse). VMEM requests per
// output row: 0.1875 (vs 0.25 at RG=2 / 79us, 0.375 at RG=1 / 100us — the
// proven binding resource). Block: 256 thr = 4 waves K-split, 64 output rows.
// Grid 256 (1 block/CU; occupancy proven non-binding R14/R16/R20).
// 2-pass LDS reduce (35 KB) + fused bias/ReLU/BN epilogue.
// ---------------------------------------------------------------------------
__global__ __launch_bounds__(256) void o72_gcn(
    const float* __restrict__ adj, const unsigned short* __restrict__ tT,
    const float* __restrict__ bias, const float* __restrict__ gamma,
    const float* __restrict__ beta, const float* __restrict__ mean,
    const float* __restrict__ var, unsigned short* __restrict__ xout)
{
    const int tid = threadIdx.x;
    const int s = tid >> 6, lane = tid & 63;
    const int rl = lane & 15, grp = lane >> 4;
    const int bid = blockIdx.x;
    const int b = bid >> 6, rb = bid & 63;
    const int row64 = rb * 64;

    const float* ar0 = adj + ((long)b * NN + row64 + rl) * (long)NN;
    const float* ar1 = ar0 + 16 * (long)NN;
    const float* ar2 = ar0 + 32 * (long)NN;
    const float* ar3 = ar0 + 48 * (long)NN;
    const unsigned short* t0 = tT + ((long)b * 64 + rl) * (long)NN;
    const unsigned short* t1 = t0 + 16 * (long)NN;
    const unsigned short* t2 = t0 + 32 * (long)NN;
    const unsigned short* t3 = t0 + 48 * (long)NN;
    const int m0 = s * 1024 + grp * 8;

    f32x4 p0 = {}, p1 = {}, p2 = {}, p3 = {};   // rg0
    f32x4 q0 = {}, q1 = {}, q2 = {}, q3 = {};   // rg1
    f32x4 r0 = {}, r1 = {}, r2v = {}, r3 = {};  // rg2
    f32x4 w0 = {}, w1 = {}, w2 = {}, w3 = {};   // rg3

    for (int it = 0; it < 32; ++it) {
        const int m = m0 + it * 32;
        short8 A0 = *(const short8*)(t0 + m);
        short8 A1 = *(const short8*)(t1 + m);
        short8 A2 = *(const short8*)(t2 + m);
        short8 A3 = *(const short8*)(t3 + m);
        short8 B0 = pk8(*(const f32x4*)(ar0 + m), *(const f32x4*)(ar0 + m + 4));
        short8 B1 = pk8(*(const f32x4*)(ar1 + m), *(const f32x4*)(ar1 + m + 4));
        short8 B2 = pk8(*(const f32x4*)(ar2 + m), *(const f32x4*)(ar2 + m + 4));
        short8 B3 = pk8(*(const f32x4*)(ar3 + m), *(const f32x4*)(ar3 + m + 4));
        p0 = __builtin_amdgcn_mfma_f32_16x16x32_bf16(A0, B0, p0, 0, 0, 0);
        p1 = __builtin_amdgcn_mfma_f32_16x16x32_bf16(A1, B0, p1, 0, 0, 0);
        p2 = __builtin_amdgcn_mfma_f32_16x16x32_bf16(A2, B0, p2, 0, 0, 0);
        p3 = __builtin_amdgcn_mfma_f32_16x16x32_bf16(A3, B0, p3, 0, 0, 0);
        q0 = __builtin_amdgcn_mfma_f32_16x16x32_bf16(A0, B1, q0, 0, 0, 0);
        q1 = __builtin_amdgcn_mfma_f32_16x16x32_bf16(A1, B1, q1, 0, 0, 0);
        q2 = __builtin_amdgcn_mfma_f32_16x16x32_bf16(A2, B1, q2, 0, 0, 0);
        q3 = __builtin_amdgcn_mfma_f32_16x16x32_bf16(A3, B1, q3, 0, 0, 0);
        r0 = __builtin_amdgcn_mfma_f32_16x16x32_bf16(A0, B2, r0, 0, 0, 0);
        r1 = __builtin_amdgcn_mfma_f32_16x16x32_bf16(A1, B2, r1, 0, 0, 0);
        r2v = __builtin_amdgcn_mfma_f32_16x16x32_bf16(A2, B2, r2v, 0, 0, 0);
        r3 = __builtin_amdgcn_mfma_f32_16x16x32_bf16(A3, B2, r3, 0, 0, 0);
        w0 = __builtin_amdgcn_mfma_f32_16x16x32_bf16(A0, B3, w0, 0, 0, 0);
        w1 = __builtin_amdgcn_mfma_f32_16x16x32_bf16(A1, B3, w1, 0, 0, 0);
        w2 = __builtin_amdgcn_mfma_f32_16x16x32_bf16(A2, B3, w2, 0, 0, 0);
        w3 = __builtin_amdgcn_mfma_f32_16x16x32_bf16(A3, B3, w3, 0, 0, 0);
    }

    __shared__ float red[4][2][16][68];
    const int rr = tid >> 4, cq = (tid & 15) * 4;
    f32x4 bi = *(const f32x4*)(bias + cq);
    f32x4 mn = *(const f32x4*)(mean + cq);
    f32x4 vr = *(const f32x4*)(var + cq);
    f32x4 gm = *(const f32x4*)(gamma + cq);
    f32x4 bt = *(const f32x4*)(beta + cq);
    f32x4 scv;
    for (int q = 0; q < 4; ++q) scv[q] = gm[q] / sqrtf(vr[q] + BN_EPS);

    for (int pass = 0; pass < 2; ++pass) {
        if (pass == 0) {
            *(f32x4*)&red[s][0][rl][ 0 + grp * 4] = p0;
            *(f32x4*)&red[s][0][rl][16 + grp * 4] = p1;
            *(f32x4*)&red[s][0][rl][32 + grp * 4] = p2;
            *(f32x4*)&red[s][0][rl][48 + grp * 4] = p3;
            *(f32x4*)&red[s][1][rl][ 0 + grp * 4] = q0;
            *(f32x4*)&red[s][1][rl][16 + grp * 4] = q1;
            *(f32x4*)&red[s][1][rl][32 + grp * 4] = q2;
            *(f32x4*)&red[s][1][rl][48 + grp * 4] = q3;
        } else {
            *(f32x4*)&red[s][0][rl][ 0 + grp * 4] = r0;
            *(f32x4*)&red[s][0][rl][16 + grp * 4] = r1;
            *(f32x4*)&red[s][0][rl][32 + grp * 4] = r2v;
            *(f32x4*)&red[s][0][rl][48 + grp * 4] = r3;
            *(f32x4*)&red[s][1][rl][ 0 + grp * 4] = w0;
            *(f32x4*)&red[s][1][rl][16 + grp * 4] = w1;
            *(f32x4*)&red[s][1][rl][32 + grp * 4] = w2;
            *(f32x4*)&red[s][1][rl][48 + grp * 4] = w3;
        }
        __syncthreads();
        for (int rg2 = 0; rg2 < 2; ++rg2) {
            f32x4 v = *(const f32x4*)&red[0][rg2][rr][cq];
            v += *(const f32x4*)&red[1][rg2][rr][cq];
            v += *(const f32x4*)&red[2][rg2][rr][cq];
            v += *(const f32x4*)&red[3][rg2][rr][cq];
            float o[4];
            for (int q = 0; q < 4; ++q) {
                float h = v[q] + bi[q];
                h = h > 0.f ? h : 0.f;
                o[q] = (h - mn[q]) * scv[q] + bt[q];
            }
            u32x2 o2;
            o2.x = (unsigned)f2bf(o[0]) | ((unsigned)f2bf(o[1]) << 16);
            o2.y = (unsigned)f2bf(o[2]) | ((unsigned)f2bf(o[3]) << 16);
            const int row = row64 + (pass * 2 + rg2) * 16 + rr;
            *(u32x2*)(xout + ((long)b * NN + row) * 64 + cq) = o2;
        }
        __syncthreads();
    }
}

// ---------------------------------------------------------------------------
// Feature transform: tT[b][c][n] = sum_k xin[b][n][k] * W[k][c]  (bf16 out)
// ---------------------------------------------------------------------------
__global__ __launch_bounds__(256) void h72_feat32(
    const float* __restrict__ xin, const float* __restrict__ W,
    unsigned short* __restrict__ tT)
{
    __shared__ float xs[64][68];
    __shared__ float Ws[64][68];
    const int tid = threadIdx.x;
    const int bid = blockIdx.x;
    const int b = bid >> 6, nb = bid & 63;
    {
        const int rr = tid >> 2, kq = (tid & 3) * 16;
        const float* xp = xin + ((long)b * NN + nb * 64 + rr) * 64 + kq;
        const float* wp = W + rr * 64 + kq;
        for (int j = 0; j < 4; ++j) {
            *(f32x4*)&xs[rr][kq + j * 4] = *(const f32x4*)(xp + j * 4);
            *(f32x4*)&Ws[rr][kq + j * 4] = *(const f32x4*)(wp + j * 4);
        }
    }
    __syncthreads();
    const int c = tid >> 2, n0 = (tid & 3) * 16;
    float outv[16];
    for (int j = 0; j < 16; ++j) outv[j] = 0.f;
    for (int kt = 0; kt < 4; ++kt) {
        float wc[16];
#pragma unroll
        for (int kk = 0; kk < 16; ++kk) wc[kk] = Ws[kt * 16 + kk][c];
#pragma unroll
        for (int j = 0; j < 16; ++j)
#pragma unroll
            for (int kk = 0; kk < 16; ++kk)
                outv[j] += xs[n0 + j][kt * 16 + kk] * wc[kk];
    }
    unsigned short* tp = tT + ((long)b * 64 + c) * (long)NN + nb * 64 + n0;
#pragma unroll
    for (int j = 0; j < 16; j += 2)
        *(unsigned*)(tp + j) =
            (unsigned)f2bf(outv[j]) | ((unsigned)f2bf(outv[j + 1]) << 16);
}

__global__ __launch_bounds__(256) void h72_featbf(
    const unsigned short* __restrict__ xin, const float* __restrict__ W,
    unsigned short* __restrict__ tT)
{
    __shared__ float xs[64][68];
    __shared__ float Ws[64][68];
    const int tid = threadIdx.x;
    const int bid = blockIdx.x;
    const int b = bid >> 6, nb = bid & 63;
    {
        const int rr = tid >> 2, kq = (tid & 3) * 16;
        const unsigned short* xp = xin + ((long)b * NN + nb * 64 + rr) * 64 + kq;
        const float* wp = W + rr * 64 + kq;
        short8 v0 = *(const short8*)(xp);
        short8 v1 = *(const short8*)(xp + 8);
        for (int j = 0; j < 8; ++j) {
            xs[rr][kq + j]     = bf2f((unsigned short)v0[j]);
            xs[rr][kq + 8 + j] = bf2f((unsigned short)v1[j]);
        }
        for (int j = 0; j < 4; ++j)
            *(f32x4*)&Ws[rr][kq + j * 4] = *(const f32x4*)(wp + j * 4);
    }
    __syncthreads();
    const int c = tid >> 2, n0 = (tid & 3) * 16;
    float outv[16];
    for (int j = 0; j < 16; ++j) outv[j] = 0.f;
    for (int kt = 0; kt < 4; ++kt) {
        float wc[16];
#pragma unroll
        for (int kk = 0; kk < 16; ++kk) wc[kk] = Ws[kt * 16 + kk][c];
#pragma unroll
        for (int j = 0; j < 16; ++j)
#pragma unroll
            for (int kk = 0; kk < 16; ++kk)
                outv[j] += xs[n0 + j][kt * 16 + kk] * wc[kk];
    }
    unsigned short* tp = tT + ((long)b * 64 + c) * (long)NN + nb * 64 + n0;
#pragma unroll
    for (int j = 0; j < 16; j += 2)
        *(unsigned*)(tp + j) =
            (unsigned)f2bf(outv[j]) | ((unsigned)f2bf(outv[j + 1]) << 16);
}

// ---------------------------------------------------------------------------
// Final MLP: out = relu(concat(x1,x2,x3) @ Wl + bl) -> FLOAT32 output
// ---------------------------------------------------------------------------
__global__ __launch_bounds__(256) void h72_mlp(
    const unsigned short* __restrict__ x1, const unsigned short* __restrict__ x2,
    const unsigned short* __restrict__ x3, const float* __restrict__ Wl,
    const float* __restrict__ bl, float* __restrict__ out)
{
    __shared__ float hs[64][196];
    const int tid = threadIdx.x;
    const int bid = blockIdx.x;
    const int b = bid >> 6, nb = bid & 63;
    {
        const int rr = tid >> 2, kq = (tid & 3) * 16;
        const long base = ((long)b * NN + nb * 64 + rr) * 64 + kq;
        short8 u0 = *(const short8*)(x1 + base);
        short8 u1 = *(const short8*)(x1 + base + 8);
        short8 v0 = *(const short8*)(x2 + base);
        short8 v1 = *(const short8*)(x2 + base + 8);
        short8 w0 = *(const short8*)(x3 + base);
        short8 w1 = *(const short8*)(x3 + base + 8);
        for (int j = 0; j < 8; ++j) {
            hs[rr][  0 + kq + j]     = bf2f((unsigned short)u0[j]);
            hs[rr][  0 + kq + 8 + j] = bf2f((unsigned short)u1[j]);
            hs[rr][ 64 + kq + j]     = bf2f((unsigned short)v0[j]);
            hs[rr][ 64 + kq + 8 + j] = bf2f((unsigned short)v1[j]);
            hs[rr][128 + kq + j]     = bf2f((unsigned short)w0[j]);
            hs[rr][128 + kq + 8 + j] = bf2f((unsigned short)w1[j]);
        }
    }
    __syncthreads();
    const int c = tid >> 2, n0 = (tid & 3) * 16;
    float acc[16];
    const float blc = bl[c];
    for (int j = 0; j < 16; ++j) acc[j] = blc;
    for (int kt = 0; kt < 12; ++kt) {
        float wc[16];
#pragma unroll
        for (int kk = 0; kk < 16; ++kk) wc[kk] = Wl[(kt * 16 + kk) * 64 + c];
#pragma unroll
        for (int j = 0; j < 16; ++j)
#pragma unroll
            for (int kk = 0; kk < 16; ++kk)
                acc[j] += hs[n0 + j][kt * 16 + kk] * wc[kk];
    }
    float* op = out + ((long)b * NN + nb * 64 + n0) * 64 + c;
#pragma unroll
    for (int j = 0; j < 16; ++j) {
        float v2 = acc[j] > 0.f ? acc[j] : 0.f;
        op[j * 64] = v2;
    }
}

// ---------------------------------------------------------------------------
extern "C" void kernel_launch(void* const* d_in, const int* in_sizes, int n_in,
                              void* d_out, int out_size, void* d_ws, size_t ws_size,
                              hipStream_t stream)
{
    (void)in_sizes; (void)n_in; (void)out_size; (void)ws_size;
    const float* x   = (const float*)d_in[0];
    const float* adj = (const float*)d_in[1];
    const float* W1  = (const float*)d_in[2];
    const float* b1  = (const float*)d_in[3];
    const float* g1  = (const float*)d_in[4];
    const float* be1 = (const float*)d_in[5];
    const float* m1  = (const float*)d_in[6];
    const float* v1  = (const float*)d_in[7];
    const float* W2  = (const float*)d_in[8];
    const float* b2  = (const float*)d_in[9];
    const float* g2  = (const float*)d_in[10];
    const float* be2 = (const float*)d_in[11];
    const float* m2  = (const float*)d_in[12];
    const float* v2  = (const float*)d_in[13];
    const float* W3  = (const float*)d_in[14];
    const float* b3  = (const float*)d_in[15];
    const float* g3  = (const float*)d_in[16];
    const float* be3 = (const float*)d_in[17];
    const float* m3  = (const float*)d_in[18];
    const float* v3  = (const float*)d_in[19];
    const float* Wl  = (const float*)d_in[20];
    const float* bl  = (const float*)d_in[21];

    // OUTPUT IS FLOAT32: 1048576 floats = 4 MB. tT (bf16, 2 MB) lives in
    // d_out's second half; h72_mlp overwrites all of d_out last.
    float* out = (float*)d_out;
    unsigned short* tT = (unsigned short*)(out + 524288);

    char* ws = (char*)d_ws;
    unsigned short* x1 = (unsigned short*)(ws);
    unsigned short* x2 = (unsigned short*)(ws + 2097152);
    unsigned short* x3 = (unsigned short*)(ws + 4194304);

    h72_feat32<<<256, 256, 0, stream>>>(x, W1, tT);
    o72_gcn<<<256, 256, 0, stream>>>(adj, tT, b1, g1, be1, m1, v1, x1);

    h72_featbf<<<256, 256, 0, stream>>>(x1, W2, tT);
    o72_gcn<<<256, 256, 0, stream>>>(adj, tT, b2, g2, be2, m2, v2, x2);

    h72_featbf<<<256, 256, 0, stream>>>(x2, W3, tT);
    o72_gcn<<<256, 256, 0, stream>>>(adj, tT, b3, g3, be3, m3, v3, x3);

    h72_mlp<<<256, 256, 0, stream>>>(x1, x2, x3, Wl, bl, out);
}